// Round 5
// baseline (177.864 us; speedup 1.0000x reference)
//
#include <hip/hip_runtime.h>

typedef __bf16 bf16x8 __attribute__((ext_vector_type(8)));
typedef float f32x4 __attribute__((ext_vector_type(4)));

// workspace layout (bytes):
//   Kt : [125][288][32] bf16 (LINEAR) at offset 0        (2,304,000 B)
//   xb : [2][36][36][36][32] bf16 at offset 2,304,000    (5,971,968 B)
#define KT_BYTES 2304000
#define NS 18432   // one B slice (288*32*2 B)
#define NACT 81    // active voxels (r^2 <= 6)

__device__ __forceinline__ unsigned short f2bf(float f) {
    unsigned int u = __builtin_bit_cast(unsigned int, f);
    unsigned int r = (u + 0x7fffu + ((u >> 16) & 1u)) >> 16;
    return (unsigned short)r;
}

__device__ __forceinline__ float sus(float x) {
    return x > 0.0f ? expf(-1.0f / x) : 0.0f;
}

// ---- active-voxel table ----
struct VoxTab { int kt[NACT]; int xb[NACT]; };
constexpr VoxTab mk_tab() {
    VoxTab t{};
    int n = 0;
    for (int dx = 0; dx < 5; dx++)
        for (int dy = 0; dy < 5; dy++)
            for (int dz = 0; dz < 5; dz++) {
                int a = dx - 2, b = dy - 2, c = dz - 2;
                if (a * a + b * b + c * c <= 6) {
                    t.kt[n] = (dx * 25 + dy * 5 + dz) * NS;      // byte offset into Kt
                    t.xb[n] = ((dx * 36 + dy) * 36 + dz) * 32;   // short offset into xb
                    n++;
                }
            }
    return t;
}
__constant__ VoxTab TAB = mk_tab();

// ---- build conv kernel Kt[v][o][ci] (bf16, linear) ----
__global__ __launch_bounds__(512) void build_kt(const float* __restrict__ w0,
                                                const float* __restrict__ w1,
                                                const float* __restrict__ w2,
                                                const float* __restrict__ wlin,
                                                unsigned short* __restrict__ kt) {
    __shared__ float lw[24576];   // [3][8][32][32] floats = 96 KB
    const int tid = threadIdx.x;
    {
        const float4* s0 = (const float4*)w0;
        const float4* s1 = (const float4*)w1;
        const float4* s2 = (const float4*)w2;
        for (int u = tid; u < 6144; u += 512) {
            int wsel = u >> 11, r = u & 2047;
            float4 v = (wsel == 0 ? s0[r] : (wsel == 1 ? s1[r] : s2[r]));
            ((float4*)lw)[u] = v;
        }
    }
    __syncthreads();

    const int v = blockIdx.x;
    const int dx = v / 25, dy = (v / 5) % 5, dz = v % 5;
    const float lx = (float)(dx - 2), ly = (float)(dy - 2), lz = (float)(dz - 2);
    const float nr = sqrtf(lx * lx + ly * ly + lz * lz);

    float emb[8];
    const float tt = nr * (9.0f / 2.5f);
    const float C = 1.14136f * expf(2.0f);
    #pragma unroll
    for (int j = 1; j <= 8; j++) {
        float d = tt - (float)j;
        emb[j - 1] = C * sus(d + 1.0f) * sus(1.0f - d);
    }

    float ux = 0.f, uy = 0.f, uz = 0.f;
    if (nr > 0.0f) { ux = lx / nr; uy = ly / nr; uz = lz / nr; }
    float Y[9];
    const float s3 = 1.7320508075688772f, s15 = 3.872983346207417f;
    Y[0] = 1.0f;
    Y[1] = s3 * uy; Y[2] = s3 * uz; Y[3] = s3 * ux;
    Y[4] = s15 * ux * uy;
    Y[5] = s15 * uy * uz;
    Y[6] = 1.1180339887498949f * (2.0f * uz * uz - ux * ux - uy * uy);
    Y[7] = s15 * ux * uz;
    Y[8] = 0.5f * s15 * (ux * ux - uy * uy);

    const float rfan = 0.17677669529663687f;  // 1/sqrt(32)

    for (int e = tid; e < 9216; e += 512) {
        const int ci = e / 288, o = e % 288;   // o fast -> conflict-free LDS reads
        int wsel, co, yi;
        if (o < 32)       { wsel = 0; co = o; yi = 0; }
        else if (o < 128) { int t = o - 32;  wsel = 1; co = t / 3; yi = 1 + t % 3; }
        else              { int t = o - 128; wsel = 2; co = t / 5; yi = 4 + t % 5; }
        const float* w = lw + wsel * 8192;
        float s = 0.0f;
        #pragma unroll
        for (int k = 0; k < 8; k++) s += emb[k] * w[k * 1024 + ci * 32 + co];
        float val = s * (1.0f / 125.0f) * Y[yi] * rfan;
        if (v == 62) val = (o < 32) ? wlin[ci * 32 + o] * rfan : 0.0f;   // center override
        kt[v * 9216 + o * 32 + ci] = f2bf(val);   // LINEAR layout
    }
}

// ---- pad + convert x to bf16 (16B stores): xb[n][36][36][36][32] ----
__global__ void pad_x2(const float* __restrict__ x, unsigned short* __restrict__ xb) {
    int u = blockIdx.x * blockDim.x + threadIdx.x;   // one 16B unit (8 bf16)
    if (u >= 373248) return;
    const int ci8 = u & 3;
    int t = u >> 2;
    const int pz = t % 36; t /= 36;
    const int py = t % 36; t /= 36;
    const int px = t % 36; const int nn = t / 36;
    const int gx = px - 2, gy = py - 2, gz = pz - 2;
    uint4 ov = {0u, 0u, 0u, 0u};
    if ((unsigned)gx < 32u && (unsigned)gy < 32u && (unsigned)gz < 32u) {
        const float* src = x + ((((size_t)nn * 32 + gx) * 32 + gy) * 32 + gz) * 32 + ci8 * 8;
        float4 f0 = ((const float4*)src)[0];
        float4 f1 = ((const float4*)src)[1];
        ov.x = (unsigned)f2bf(f0.x) | ((unsigned)f2bf(f0.y) << 16);
        ov.y = (unsigned)f2bf(f0.z) | ((unsigned)f2bf(f0.w) << 16);
        ov.z = (unsigned)f2bf(f1.x) | ((unsigned)f2bf(f1.y) << 16);
        ov.w = (unsigned)f2bf(f1.z) | ((unsigned)f2bf(f1.w) << 16);
    }
    ((uint4*)xb)[u] = ov;
}

// ---- conv: implicit GEMM, block = 256 positions x 288 outputs, 8 waves ----
// NO LDS, NO staging: A and B both read straight from global (everything is
// L2-resident: Kt 2.3 MB/XCD-L2, xb slab ~0.75 MB/XCD). Waves run free;
// a raw s_barrier every 3 voxels bounds drift so the B slice stays L1-hot.
__global__ __launch_bounds__(512, 2) void conv_mfma(const unsigned short* __restrict__ xb,
                                                    const unsigned short* __restrict__ kt,
                                                    float* __restrict__ out) {
    const int tid = threadIdx.x;
    const int lane = tid & 63;
    const int wv = tid >> 6;
    const int l15 = lane & 15, l16 = lane >> 4;
    const int wm = wv & 3, wn = wv >> 2;
    const int o0 = wn * 144;

    // XCD-bijective swizzle: 256 blocks = 8 XCDs x 32 -> each XCD one x-slab
    const int b = blockIdx.x;
    const int sw = (b & 7) * 32 + (b >> 3);
    const int nn = sw >> 7;
    const int X0 = 2 * ((sw >> 3) & 15);
    const int Y0 = 4 * (sw & 7);

    const unsigned short* xbase = xb + (size_t)nn * 1492992;

    // per-lane A global offsets (shorts), frag s: (y-off s>>1, z-half s&1)
    int aoff[4];
    #pragma unroll
    for (int s = 0; s < 4; s++) {
        int xw = X0 + (wm >> 1);
        int yw = Y0 + (wm & 1) * 2 + (s >> 1);
        int zb = (s & 1) * 16 + l15;
        aoff[s] = ((xw * 36 + yw) * 36 + zb) * 32 + l16 * 8;
    }
    // per-lane B global base (bytes): wave reads contiguous 1 KB per frag
    const char* kbase = (const char*)kt + (o0 + l15) * 64 + l16 * 16;

    f32x4 acc[4][9];
    #pragma unroll
    for (int i = 0; i < 4; i++)
        #pragma unroll
        for (int j = 0; j < 9; j++)
            acc[i][j] = (f32x4){0.f, 0.f, 0.f, 0.f};

    #pragma unroll 1
    for (int g = 0; g < 27; g++) {
        #pragma unroll
        for (int q = 0; q < 3; q++) {
            const int k = g * 3 + q;
            const unsigned short* ax = xbase + TAB.xb[k];
            const char* kb = kbase + TAB.kt[k];
            bf16x8 A[4];
            #pragma unroll
            for (int s = 0; s < 4; s++)
                A[s] = *(const bf16x8*)(ax + aoff[s]);
            #pragma unroll
            for (int nt = 0; nt < 9; nt++) {
                bf16x8 B = *(const bf16x8*)(kb + nt * 1024);
                #pragma unroll
                for (int s = 0; s < 4; s++)
                    acc[s][nt] = __builtin_amdgcn_mfma_f32_16x16x32_bf16(A[s], B, acc[s][nt], 0, 0, 0);
            }
        }
        __builtin_amdgcn_s_barrier();   // rendezvous only (no shared data) — keeps B L1-hot
    }

    // ---- epilogue: D row = 4*l16 + r (m), col = l15 (n) ----
    #pragma unroll
    for (int s = 0; s < 4; s++) {
        const int x = X0 + (wm >> 1);
        const int y = Y0 + (wm & 1) * 2 + (s >> 1);
        #pragma unroll
        for (int r = 0; r < 4; r++) {
            int z = (s & 1) * 16 + l16 * 4 + r;
            size_t base = ((((size_t)nn * 32 + x) * 32 + y) * 32 + z) * 288 + o0 + l15;
            #pragma unroll
            for (int nt = 0; nt < 9; nt++)
                out[base + nt * 16] = acc[s][nt][r];
        }
    }
}

extern "C" void kernel_launch(void* const* d_in, const int* in_sizes, int n_in,
                              void* d_out, int out_size, void* d_ws, size_t ws_size,
                              hipStream_t stream) {
    const float* x    = (const float*)d_in[0];
    const float* w0   = (const float*)d_in[1];
    const float* w1   = (const float*)d_in[2];
    const float* w2   = (const float*)d_in[3];
    const float* wlin = (const float*)d_in[4];
    unsigned short* kt = (unsigned short*)d_ws;
    unsigned short* xb = (unsigned short*)((char*)d_ws + KT_BYTES);
    float* out = (float*)d_out;

    hipLaunchKernelGGL(build_kt, dim3(125), dim3(512), 0, stream, w0, w1, w2, wlin, kt);
    hipLaunchKernelGGL(pad_x2, dim3(1458), dim3(256), 0, stream, x, xb);
    hipLaunchKernelGGL(conv_mfma, dim3(256), dim3(512), 0, stream, xb, kt, out);
}

// Round 6
// 110.198 us; speedup vs baseline: 1.6140x; 1.6140x over previous
//
#include <hip/hip_runtime.h>

typedef __bf16 bf16x8 __attribute__((ext_vector_type(8)));
typedef float f32x4 __attribute__((ext_vector_type(4)));

// workspace layout (bytes):
//   Kt : [125][288][32] bf16 (pre-swizzled within each 18432-B slice) at offset 0
//   xb : [2][36][36][36][32] bf16 at offset 2,304,000
#define KT_BYTES 2304000
#define NS 18432   // one B slice (288*32*2 B)
#define NV 84      // 81 active voxels + 3 dummies (v=0 slice is exactly zero)

__device__ __forceinline__ unsigned short f2bf(float f) {
    unsigned int u = __builtin_bit_cast(unsigned int, f);
    unsigned int r = (u + 0x7fffu + ((u >> 16) & 1u)) >> 16;
    return (unsigned short)r;
}

__device__ __forceinline__ float sus(float x) {
    return x > 0.0f ? expf(-1.0f / x) : 0.0f;
}

// ---- active-voxel table (81 voxels with r^2 <= 6) + dummy pad ----
struct VoxTab { int kt[NV]; int xb[NV]; };
constexpr VoxTab mk_tab() {
    VoxTab t{};
    int n = 0;
    for (int dx = 0; dx < 5; dx++)
        for (int dy = 0; dy < 5; dy++)
            for (int dz = 0; dz < 5; dz++) {
                int a = dx - 2, b = dy - 2, c = dz - 2;
                if (a * a + b * b + c * c <= 6) {
                    t.kt[n] = (dx * 25 + dy * 5 + dz) * NS;      // byte offset into Kt
                    t.xb[n] = ((dx * 36 + dy) * 36 + dz) * 32;   // short offset into xb
                    n++;
                }
            }
    for (; n < NV; n++) { t.kt[n] = 0; t.xb[n] = 0; }
    return t;
}
__constant__ VoxTab TAB = mk_tab();

// ---- build conv kernel Kt[v][o][ci] (bf16, PRE-SWIZZLED) ----
__global__ __launch_bounds__(512) void build_kt(const float* __restrict__ w0,
                                                const float* __restrict__ w1,
                                                const float* __restrict__ w2,
                                                const float* __restrict__ wlin,
                                                unsigned short* __restrict__ kt) {
    __shared__ float lw[24576];   // [3][8][32][32] floats = 96 KB
    const int tid = threadIdx.x;
    {
        const float4* s0 = (const float4*)w0;
        const float4* s1 = (const float4*)w1;
        const float4* s2 = (const float4*)w2;
        for (int u = tid; u < 6144; u += 512) {
            int wsel = u >> 11, r = u & 2047;
            float4 v = (wsel == 0 ? s0[r] : (wsel == 1 ? s1[r] : s2[r]));
            ((float4*)lw)[u] = v;
        }
    }
    __syncthreads();

    const int v = blockIdx.x;
    const int dx = v / 25, dy = (v / 5) % 5, dz = v % 5;
    const float lx = (float)(dx - 2), ly = (float)(dy - 2), lz = (float)(dz - 2);
    const float nr = sqrtf(lx * lx + ly * ly + lz * lz);

    float emb[8];
    const float tt = nr * (9.0f / 2.5f);
    const float C = 1.14136f * expf(2.0f);
    #pragma unroll
    for (int j = 1; j <= 8; j++) {
        float d = tt - (float)j;
        emb[j - 1] = C * sus(d + 1.0f) * sus(1.0f - d);
    }

    float ux = 0.f, uy = 0.f, uz = 0.f;
    if (nr > 0.0f) { ux = lx / nr; uy = ly / nr; uz = lz / nr; }
    float Y[9];
    const float s3 = 1.7320508075688772f, s15 = 3.872983346207417f;
    Y[0] = 1.0f;
    Y[1] = s3 * uy; Y[2] = s3 * uz; Y[3] = s3 * ux;
    Y[4] = s15 * ux * uy;
    Y[5] = s15 * uy * uz;
    Y[6] = 1.1180339887498949f * (2.0f * uz * uz - ux * ux - uy * uy);
    Y[7] = s15 * ux * uz;
    Y[8] = 0.5f * s15 * (ux * ux - uy * uy);

    const float rfan = 0.17677669529663687f;  // 1/sqrt(32)

    for (int e = tid; e < 9216; e += 512) {
        const int ci = e / 288, o = e % 288;
        int wsel, co, yi;
        if (o < 32)       { wsel = 0; co = o; yi = 0; }
        else if (o < 128) { int t = o - 32;  wsel = 1; co = t / 3; yi = 1 + t % 3; }
        else              { int t = o - 128; wsel = 2; co = t / 5; yi = 4 + t % 5; }
        const float* w = lw + wsel * 8192;
        float s = 0.0f;
        #pragma unroll
        for (int k = 0; k < 8; k++) s += emb[k] * w[k * 1024 + ci * 32 + co];
        float val = s * (1.0f / 125.0f) * Y[yi] * rfan;
        if (v == 62) val = (o < 32) ? wlin[ci * 32 + o] * rfan : 0.0f;   // center override
        int r = o * 64 + ci * 2;                   // logical byte addr in slice
        int rs = r ^ (((r >> 7) & 7) << 4);        // pre-apply LDS swizzle (involution)
        kt[v * 9216 + (rs >> 1)] = f2bf(val);
    }
}

// ---- pad + convert x to bf16 (16B stores): xb[n][36][36][36][32] ----
__global__ void pad_x2(const float* __restrict__ x, unsigned short* __restrict__ xb) {
    int u = blockIdx.x * blockDim.x + threadIdx.x;   // one 16B unit (8 bf16)
    if (u >= 373248) return;
    const int ci8 = u & 3;
    int t = u >> 2;
    const int pz = t % 36; t /= 36;
    const int py = t % 36; t /= 36;
    const int px = t % 36; const int nn = t / 36;
    const int gx = px - 2, gy = py - 2, gz = pz - 2;
    uint4 ov = {0u, 0u, 0u, 0u};
    if ((unsigned)gx < 32u && (unsigned)gy < 32u && (unsigned)gz < 32u) {
        const float* src = x + ((((size_t)nn * 32 + gx) * 32 + gy) * 32 + gz) * 32 + ci8 * 8;
        float4 f0 = ((const float4*)src)[0];
        float4 f1 = ((const float4*)src)[1];
        ov.x = (unsigned)f2bf(f0.x) | ((unsigned)f2bf(f0.y) << 16);
        ov.y = (unsigned)f2bf(f0.z) | ((unsigned)f2bf(f0.w) << 16);
        ov.z = (unsigned)f2bf(f1.x) | ((unsigned)f2bf(f1.y) << 16);
        ov.w = (unsigned)f2bf(f1.z) | ((unsigned)f2bf(f1.w) << 16);
    }
    ((uint4*)xb)[u] = ov;
}

// ---- conv: implicit GEMM, block = 128 positions x 288 outputs, 8 waves ----
// Per wave: acc[2][9] (72 VGPR) -> 4 waves/SIMD, 2 blocks/CU (512 blocks).
// A: global, alternating reg sets. B: 4-slot LDS ring (pre-swizzled Kt),
// staged via global_load_lds; loadA-before-stage order => steady vmcnt(3).
__global__ __launch_bounds__(512, 4) void conv_mfma(const unsigned short* __restrict__ xb,
                                                    const unsigned short* __restrict__ kt,
                                                    float* __restrict__ out) {
    __shared__ __align__(16) char lds[4 * NS];
    const int tid = threadIdx.x;
    const int lane = tid & 63;
    const int wv = tid >> 6;
    const int l15 = lane & 15, l16 = lane >> 4;
    const int wm = wv & 3, wn = wv >> 2;
    const int o0 = wn * 144;

    // XCD-bijective swizzle: 512 blocks = 8 XCDs x 64
    const int b = blockIdx.x;
    const int sw = (b & 7) * 64 + (b >> 3);
    const int nn = sw >> 8;
    const int X0 = 2 * ((sw >> 4) & 15);
    const int Y0 = 2 * (sw & 15);

    const unsigned short* xbase = xb + (size_t)nn * 1492992;

    // A: wave wm covers (x = X0+(wm>>1), y = Y0+(wm&1)), z-halves s=0,1
    const int axy = ((X0 + (wm >> 1)) * 36 + (Y0 + (wm & 1))) * 36;
    const int aoff0 = (axy + l15) * 32 + l16 * 8;     // s=0 (z 0..15); s=1 adds 16*32 shorts

    // B LDS base (bytes, swizzled); frag nt at +nt*1024 (swizzle indep. of nt)
    int bbase = (o0 + l15) * 64 + l16 * 16;
    bbase ^= ((bbase >> 7) & 7) << 4;

    auto stageB = [&](int ktByte, int slot) {
        const char* src = (const char*)kt + ktByte + wv * 2304;
        char* dst = lds + slot * NS + wv * 2304;
        __builtin_amdgcn_global_load_lds(
            (const __attribute__((address_space(1))) void*)(src + lane * 16),
            (__attribute__((address_space(3))) void*)dst, 16, 0, 0);
        __builtin_amdgcn_global_load_lds(
            (const __attribute__((address_space(1))) void*)(src + 1024 + lane * 16),
            (__attribute__((address_space(3))) void*)(dst + 1024), 16, 0, 0);
        __builtin_amdgcn_global_load_lds(
            (const __attribute__((address_space(1))) void*)(src + 2048 + lane * 4),
            (__attribute__((address_space(3))) void*)(dst + 2048), 4, 0, 0);
    };

    bf16x8 A0[2], A1[2];
    f32x4 acc[2][9];
    #pragma unroll
    for (int i = 0; i < 2; i++)
        #pragma unroll
        for (int j = 0; j < 9; j++)
            acc[i][j] = (f32x4){0.f, 0.f, 0.f, 0.f};

    auto loadA = [&](bf16x8* A, int xoff) {
        const unsigned short* p = xbase + aoff0 + xoff;
        A[0] = *(const bf16x8*)p;
        A[1] = *(const bf16x8*)(p + 512);   // +16 z-steps * 32 ci
    };

    auto compute = [&](bf16x8* A, int slot) {
        const char* bp = lds + slot * NS + bbase;
        #pragma unroll
        for (int nt = 0; nt < 9; nt++) {
            bf16x8 B = *(const bf16x8*)(bp + nt * 1024);
            acc[0][nt] = __builtin_amdgcn_mfma_f32_16x16x32_bf16(A[0], B, acc[0][nt], 0, 0, 0);
            acc[1][nt] = __builtin_amdgcn_mfma_f32_16x16x32_bf16(A[1], B, acc[1][nt], 0, 0, 0);
        }
    };

    // PHASE(k): vmcnt(3) [leaves only newest stage triple; A(k)+all B(k) drained];
    // barrier; loadA(k+1); stage B(k+3); compute(k).
    #define PHASE(CUR, NXT, K)                                          \
        asm volatile("s_waitcnt vmcnt(3)" ::: "memory");                \
        __builtin_amdgcn_sched_barrier(0);                              \
        __builtin_amdgcn_s_barrier();                                   \
        __builtin_amdgcn_sched_barrier(0);                              \
        loadA(NXT, TAB.xb[(K) + 1]);                                    \
        stageB(TAB.kt[(K) + 3], ((K) + 3) & 3);                         \
        compute(CUR, (K) & 3);

    // prologue: slots 0,1,2 + A(0)
    stageB(TAB.kt[0], 0);
    stageB(TAB.kt[1], 1);
    stageB(TAB.kt[2], 2);
    loadA(A0, TAB.xb[0]);

    #pragma unroll 1
    for (int g = 0; g < 40; g++) {
        const int k = g * 2;
        PHASE(A0, A1, k + 0)
        PHASE(A1, A0, k + 1)
    }
    PHASE(A0, A1, 80)   // k=80 last real voxel (loads/stages hit dummy entries)
    #undef PHASE

    // ---- epilogue: D row = 4*l16 + r (m=z), col = l15 (n) ----
    const int x = X0 + (wm >> 1);
    const int y = Y0 + (wm & 1);
    #pragma unroll
    for (int s = 0; s < 2; s++) {
        #pragma unroll
        for (int r = 0; r < 4; r++) {
            int z = s * 16 + l16 * 4 + r;
            size_t base = ((((size_t)nn * 32 + x) * 32 + y) * 32 + z) * 288 + o0 + l15;
            #pragma unroll
            for (int nt = 0; nt < 9; nt++)
                out[base + nt * 16] = acc[s][nt][r];
        }
    }
}

extern "C" void kernel_launch(void* const* d_in, const int* in_sizes, int n_in,
                              void* d_out, int out_size, void* d_ws, size_t ws_size,
                              hipStream_t stream) {
    const float* x    = (const float*)d_in[0];
    const float* w0   = (const float*)d_in[1];
    const float* w1   = (const float*)d_in[2];
    const float* w2   = (const float*)d_in[3];
    const float* wlin = (const float*)d_in[4];
    unsigned short* kt = (unsigned short*)d_ws;
    unsigned short* xb = (unsigned short*)((char*)d_ws + KT_BYTES);
    float* out = (float*)d_out;

    hipLaunchKernelGGL(build_kt, dim3(125), dim3(512), 0, stream, w0, w1, w2, wlin, kt);
    hipLaunchKernelGGL(pad_x2, dim3(1458), dim3(256), 0, stream, x, xb);
    hipLaunchKernelGGL(conv_mfma, dim3(512), dim3(512), 0, stream, xb, kt, out);
}

// Round 7
// 108.919 us; speedup vs baseline: 1.6330x; 1.0117x over previous
//
#include <hip/hip_runtime.h>

typedef __bf16 bf16x8 __attribute__((ext_vector_type(8)));
typedef float f32x4 __attribute__((ext_vector_type(4)));

// workspace layout (bytes):
//   Kt : [125][288][32] bf16 (pre-swizzled within each 18432-B slice) at offset 0
//   xb : [2][36][36][36][32] bf16 at offset 2,304,000
#define KT_BYTES 2304000
#define NS 18432   // one B slice (288*32*2 B)
#define NVT 86     // 84 voxel slots (81 active + 3 zero dummies) + 2 stage-ahead dummies

__device__ __forceinline__ unsigned short f2bf(float f) {
    unsigned int u = __builtin_bit_cast(unsigned int, f);
    unsigned int r = (u + 0x7fffu + ((u >> 16) & 1u)) >> 16;
    return (unsigned short)r;
}

__device__ __forceinline__ float sus(float x) {
    return x > 0.0f ? expf(-1.0f / x) : 0.0f;
}

// ---- active-voxel table (81 voxels with r^2 <= 6) + dummy pad (v=0 slice is zero) ----
struct VoxTab { int kt[NVT]; int xb[NVT]; };
constexpr VoxTab mk_tab() {
    VoxTab t{};
    int n = 0;
    for (int dx = 0; dx < 5; dx++)
        for (int dy = 0; dy < 5; dy++)
            for (int dz = 0; dz < 5; dz++) {
                int a = dx - 2, b = dy - 2, c = dz - 2;
                if (a * a + b * b + c * c <= 6) {
                    t.kt[n] = (dx * 25 + dy * 5 + dz) * NS;      // byte offset into Kt
                    t.xb[n] = ((dx * 36 + dy) * 36 + dz) * 32;   // short offset into xb
                    n++;
                }
            }
    for (; n < NVT; n++) { t.kt[n] = 0; t.xb[n] = 0; }
    return t;
}
__constant__ VoxTab TAB = mk_tab();

// ---- build conv kernel Kt[v][o][ci] (bf16, PRE-SWIZZLED) ----
__global__ __launch_bounds__(512) void build_kt(const float* __restrict__ w0,
                                                const float* __restrict__ w1,
                                                const float* __restrict__ w2,
                                                const float* __restrict__ wlin,
                                                unsigned short* __restrict__ kt) {
    __shared__ float lw[24576];   // [3][8][32][32] floats = 96 KB
    const int tid = threadIdx.x;
    {
        const float4* s0 = (const float4*)w0;
        const float4* s1 = (const float4*)w1;
        const float4* s2 = (const float4*)w2;
        for (int u = tid; u < 6144; u += 512) {
            int wsel = u >> 11, r = u & 2047;
            float4 v = (wsel == 0 ? s0[r] : (wsel == 1 ? s1[r] : s2[r]));
            ((float4*)lw)[u] = v;
        }
    }
    __syncthreads();

    const int v = blockIdx.x;
    const int dx = v / 25, dy = (v / 5) % 5, dz = v % 5;
    const float lx = (float)(dx - 2), ly = (float)(dy - 2), lz = (float)(dz - 2);
    const float nr = sqrtf(lx * lx + ly * ly + lz * lz);

    float emb[8];
    const float tt = nr * (9.0f / 2.5f);
    const float C = 1.14136f * expf(2.0f);
    #pragma unroll
    for (int j = 1; j <= 8; j++) {
        float d = tt - (float)j;
        emb[j - 1] = C * sus(d + 1.0f) * sus(1.0f - d);
    }

    float ux = 0.f, uy = 0.f, uz = 0.f;
    if (nr > 0.0f) { ux = lx / nr; uy = ly / nr; uz = lz / nr; }
    float Y[9];
    const float s3 = 1.7320508075688772f, s15 = 3.872983346207417f;
    Y[0] = 1.0f;
    Y[1] = s3 * uy; Y[2] = s3 * uz; Y[3] = s3 * ux;
    Y[4] = s15 * ux * uy;
    Y[5] = s15 * uy * uz;
    Y[6] = 1.1180339887498949f * (2.0f * uz * uz - ux * ux - uy * uy);
    Y[7] = s15 * ux * uz;
    Y[8] = 0.5f * s15 * (ux * ux - uy * uy);

    const float rfan = 0.17677669529663687f;  // 1/sqrt(32)

    for (int e = tid; e < 9216; e += 512) {
        const int ci = e / 288, o = e % 288;
        int wsel, co, yi;
        if (o < 32)       { wsel = 0; co = o; yi = 0; }
        else if (o < 128) { int t = o - 32;  wsel = 1; co = t / 3; yi = 1 + t % 3; }
        else              { int t = o - 128; wsel = 2; co = t / 5; yi = 4 + t % 5; }
        const float* w = lw + wsel * 8192;
        float s = 0.0f;
        #pragma unroll
        for (int k = 0; k < 8; k++) s += emb[k] * w[k * 1024 + ci * 32 + co];
        float val = s * (1.0f / 125.0f) * Y[yi] * rfan;
        if (v == 62) val = (o < 32) ? wlin[ci * 32 + o] * rfan : 0.0f;   // center override
        int r = o * 64 + ci * 2;                   // logical byte addr in slice
        int rs = r ^ (((r >> 7) & 7) << 4);        // pre-apply LDS swizzle (involution)
        kt[v * 9216 + (rs >> 1)] = f2bf(val);
    }
}

// ---- pad + convert x to bf16 (16B stores): xb[n][36][36][36][32] ----
__global__ void pad_x2(const float* __restrict__ x, unsigned short* __restrict__ xb) {
    int u = blockIdx.x * blockDim.x + threadIdx.x;   // one 16B unit (8 bf16)
    if (u >= 373248) return;
    const int ci8 = u & 3;
    int t = u >> 2;
    const int pz = t % 36; t /= 36;
    const int py = t % 36; t /= 36;
    const int px = t % 36; const int nn = t / 36;
    const int gx = px - 2, gy = py - 2, gz = pz - 2;
    uint4 ov = {0u, 0u, 0u, 0u};
    if ((unsigned)gx < 32u && (unsigned)gy < 32u && (unsigned)gz < 32u) {
        const float* src = x + ((((size_t)nn * 32 + gx) * 32 + gy) * 32 + gz) * 32 + ci8 * 8;
        float4 f0 = ((const float4*)src)[0];
        float4 f1 = ((const float4*)src)[1];
        ov.x = (unsigned)f2bf(f0.x) | ((unsigned)f2bf(f0.y) << 16);
        ov.y = (unsigned)f2bf(f0.z) | ((unsigned)f2bf(f0.w) << 16);
        ov.z = (unsigned)f2bf(f1.x) | ((unsigned)f2bf(f1.y) << 16);
        ov.w = (unsigned)f2bf(f1.z) | ((unsigned)f2bf(f1.w) << 16);
    }
    ((uint4*)xb)[u] = ov;
}

// ---- conv: implicit GEMM, block = 128 positions x 288 outputs, 8 waves ----
// 2 voxels per barrier phase: reads(2p+1) overlap MFMA tail of (2p) in-wave;
// 42 barriers. Ring 4 slots. Issue order pinned by sched_barrier(0) fences:
//   stages(6 vm) | computes | A-loads(4 vm)  =>  vmcnt(4) at phase start
// publishes both slices staged last phase, never drains in-flight A loads.
__global__ __launch_bounds__(512, 4) void conv_mfma(const unsigned short* __restrict__ xb,
                                                    const unsigned short* __restrict__ kt,
                                                    float* __restrict__ out) {
    __shared__ __align__(16) char lds[4 * NS];
    const int tid = threadIdx.x;
    const int lane = tid & 63;
    const int wv = tid >> 6;
    const int l15 = lane & 15, l16 = lane >> 4;
    const int wm = wv & 3, wn = wv >> 2;
    const int o0 = wn * 144;

    // XCD-bijective swizzle: 512 blocks = 8 XCDs x 64
    const int b = blockIdx.x;
    const int sw = (b & 7) * 64 + (b >> 3);
    const int nn = sw >> 8;
    const int X0 = 2 * ((sw >> 4) & 15);
    const int Y0 = 2 * (sw & 15);

    const unsigned short* xbase = xb + (size_t)nn * 1492992;

    // A: wave wm covers (x = X0+(wm>>1), y = Y0+(wm&1)), z-halves s=0,1
    const int axy = ((X0 + (wm >> 1)) * 36 + (Y0 + (wm & 1))) * 36;
    const int aoff0 = (axy + l15) * 32 + l16 * 8;     // s=0; s=1 adds 512 shorts

    // B LDS base (bytes, swizzled); frag nt at +nt*1024 (swizzle indep. of nt)
    int bbase = (o0 + l15) * 64 + l16 * 16;
    bbase ^= ((bbase >> 7) & 7) << 4;

    auto stageB = [&](int ktByte, int slot) {
        const char* src = (const char*)kt + ktByte + wv * 2304;
        char* dst = lds + slot * NS + wv * 2304;
        __builtin_amdgcn_global_load_lds(
            (const __attribute__((address_space(1))) void*)(src + lane * 16),
            (__attribute__((address_space(3))) void*)dst, 16, 0, 0);
        __builtin_amdgcn_global_load_lds(
            (const __attribute__((address_space(1))) void*)(src + 1024 + lane * 16),
            (__attribute__((address_space(3))) void*)(dst + 1024), 16, 0, 0);
        __builtin_amdgcn_global_load_lds(
            (const __attribute__((address_space(1))) void*)(src + 2048 + lane * 4),
            (__attribute__((address_space(3))) void*)(dst + 2048), 4, 0, 0);
    };

    bf16x8 A0[2], A1[2];
    f32x4 acc[2][9];
    #pragma unroll
    for (int i = 0; i < 2; i++)
        #pragma unroll
        for (int j = 0; j < 9; j++)
            acc[i][j] = (f32x4){0.f, 0.f, 0.f, 0.f};

    auto loadA = [&](bf16x8* A, int xoff) {
        const unsigned short* p = xbase + aoff0 + xoff;
        A[0] = *(const bf16x8*)p;
        A[1] = *(const bf16x8*)(p + 512);   // +16 z-steps * 32 ci
    };

    auto compute = [&](bf16x8* A, int slot) {
        const char* bp = lds + slot * NS + bbase;
        #pragma unroll
        for (int nt = 0; nt < 9; nt++) {
            bf16x8 B = *(const bf16x8*)(bp + nt * 1024);
            acc[0][nt] = __builtin_amdgcn_mfma_f32_16x16x32_bf16(A[0], B, acc[0][nt], 0, 0, 0);
            acc[1][nt] = __builtin_amdgcn_mfma_f32_16x16x32_bf16(A[1], B, acc[1][nt], 0, 0, 0);
        }
    };

    // prologue: slots 0,1 + A(0),A(1)
    stageB(TAB.kt[0], 0);
    stageB(TAB.kt[1], 1);
    loadA(A0, TAB.xb[0]);
    loadA(A1, TAB.xb[1]);

    #pragma unroll 1
    for (int p = 0; p < 42; p++) {
        const int k = 2 * p;
        asm volatile("s_waitcnt vmcnt(4)" ::: "memory");
        __builtin_amdgcn_sched_barrier(0);
        __builtin_amdgcn_s_barrier();
        __builtin_amdgcn_sched_barrier(0);
        // stages first (6 vm ops)
        stageB(TAB.kt[k + 2], (k + 2) & 3);
        stageB(TAB.kt[k + 3], (k + 3) & 3);
        __builtin_amdgcn_sched_barrier(0);
        // compute 2 voxels (ds_reads of voxel k+1 overlap MFMA tail of voxel k)
        __builtin_amdgcn_s_setprio(1);
        compute(A0, k & 3);
        compute(A1, (k + 1) & 3);
        __builtin_amdgcn_s_setprio(0);
        __builtin_amdgcn_sched_barrier(0);
        // A loads last (4 vm ops) -> newest at next phase's vmcnt(4)
        loadA(A0, TAB.xb[k + 2]);
        loadA(A1, TAB.xb[k + 3]);
    }

    // ---- epilogue: D row = 4*l16 + r (m=z), col = l15 (n) ----
    const int x = X0 + (wm >> 1);
    const int y = Y0 + (wm & 1);
    #pragma unroll
    for (int s = 0; s < 2; s++) {
        #pragma unroll
        for (int r = 0; r < 4; r++) {
            int z = s * 16 + l16 * 4 + r;
            size_t base = ((((size_t)nn * 32 + x) * 32 + y) * 32 + z) * 288 + o0 + l15;
            #pragma unroll
            for (int nt = 0; nt < 9; nt++)
                out[base + nt * 16] = acc[s][nt][r];
        }
    }
}

extern "C" void kernel_launch(void* const* d_in, const int* in_sizes, int n_in,
                              void* d_out, int out_size, void* d_ws, size_t ws_size,
                              hipStream_t stream) {
    const float* x    = (const float*)d_in[0];
    const float* w0   = (const float*)d_in[1];
    const float* w1   = (const float*)d_in[2];
    const float* w2   = (const float*)d_in[3];
    const float* wlin = (const float*)d_in[4];
    unsigned short* kt = (unsigned short*)d_ws;
    unsigned short* xb = (unsigned short*)((char*)d_ws + KT_BYTES);
    float* out = (float*)d_out;

    hipLaunchKernelGGL(build_kt, dim3(125), dim3(512), 0, stream, w0, w1, w2, wlin, kt);
    hipLaunchKernelGGL(pad_x2, dim3(1458), dim3(256), 0, stream, x, xb);
    hipLaunchKernelGGL(conv_mfma, dim3(512), dim3(512), 0, stream, xb, kt, out);
}